// Round 5
// baseline (581.863 us; speedup 1.0000x reference)
//
#include <hip/hip_runtime.h>

// AugmentedNeuralODE, round 18: R17 + amdgpu_waves_per_eu(2,2) hard pin.
// R16/R17 post-mortem: VGPR_Count = exactly 128 both rounds, FETCH ~1GB
// = compiler *chose* a 128-reg budget (LLVM occupancy heuristic: launch
// bounds' 2nd arg is only a MIN waves/EU, allocator targeted 4/EU) and
// spilled the ~210-reg working set. Static demand fits 256 (2 waves/EU,
// 512-reg pool). Pin min=max=2 waves/EU -> 256-reg budget, no spill.
// Everything else identical to R17: barrier-free duplicate-column 2-wave
// structure, W2 tiles 0-3 VGPR / 4-7 LDS (16KB, conflict-free b128),
// pair-fused epilogue (2 live accs), shfl_xor(8) L1 exchange, 1024x128.

#define HID 128
#define TT  8
#define F(a,b) ((float)((double)(a)/(double)(b)))
#define K2C 2.8853900817779268f        // 2*log2(e), folded into W1/b1/W2/b2

typedef __attribute__((ext_vector_type(8))) short bf16x8;
typedef __attribute__((ext_vector_type(4))) float f32x4;
typedef __attribute__((ext_vector_type(2))) float f32x2;

union Frag { bf16x8 v; unsigned short u[8]; unsigned int d[4]; };

__device__ __forceinline__ f32x2 bc(float s) { return f32x2{s, s}; }
__device__ __forceinline__ f32x2 pk_fma(f32x2 a, f32x2 b, f32x2 c) {
#if __has_builtin(__builtin_elementwise_fma)
  return __builtin_elementwise_fma(a, b, c);
#else
  return a * b + c;
#endif
}
__device__ __forceinline__ float exp2_fast(float x) {
#if __has_builtin(__builtin_amdgcn_exp2f)
  return __builtin_amdgcn_exp2f(x);
#else
  return __builtin_exp2f(x);
#endif
}
__device__ __forceinline__ unsigned short f2bf(float f) {
  unsigned u = __builtin_bit_cast(unsigned, f);
  u += 0x7FFFu + ((u >> 16) & 1u);          // RNE
  return (unsigned short)(u >> 16);
}
__device__ __forceinline__ unsigned pack2bf(float a, float b) {
#if __has_builtin(__builtin_amdgcn_cvt_pk_bf16_f32)
  auto pk = __builtin_amdgcn_cvt_pk_bf16_f32(a, b);   // v_cvt_pk_bf16_f32
  return __builtin_bit_cast(unsigned, pk);
#else
  unsigned ua = __builtin_bit_cast(unsigned, a);
  unsigned ub = __builtin_bit_cast(unsigned, b);
  ua += 0x7FFFu + ((ua >> 16) & 1u);
  ub += 0x7FFFu + ((ub >> 16) & 1u);
  return __builtin_amdgcn_perm(ub, ua, 0x07060302u);
#endif
}
// u pre-scaled by 2*log2(e): q = 1/(exp2(u)+1), separate rcp per element.
__device__ __forceinline__ f32x2 sig_q(f32x2 u) {
  f32x2 e;
  e.x = exp2_fast(u.x);
  e.y = exp2_fast(u.y);
  f32x2 d = e + bc(1.0f);
  f32x2 q;
  q.x = __builtin_amdgcn_rcpf(d.x);
  q.y = __builtin_amdgcn_rcpf(d.y);
  return q;
}
__device__ __forceinline__ f32x2 tanh_pre(f32x2 u) {   // tanh = 1 - 2q
  return pk_fma(bc(-2.0f), sig_q(u), bc(1.0f));
}
__device__ __forceinline__ float bfhi(unsigned d) {
  return __builtin_bit_cast(float, d & 0xFFFF0000u);
}
__device__ __forceinline__ float bflo(unsigned d) {
  return __builtin_bit_cast(float, d << 16);
}

__global__ __attribute__((amdgpu_waves_per_eu(2, 2)))
__launch_bounds__(128) void node_kernel(
    const float* __restrict__ r0, const float* __restrict__ tarr,
    const float* __restrict__ W1, const float* __restrict__ b1,
    const float* __restrict__ W2, const float* __restrict__ b2,
    const float* __restrict__ W3, const float* __restrict__ b3,
    float* __restrict__ out)
{
  const int tid  = (int)threadIdx.x;
  const int w    = tid >> 6;            // wave 0/1
  const int lane = tid & 63;
  const int q    = lane >> 4;           // 0..3
  const int h    = (lane >> 3) & 1;     // half within 16-col group
  const int c    = lane & 7;            // my sample (0..7 within wave)
  const int m16  = lane & 15;           // MFMA row/col index
  const int s    = (int)blockIdx.x * 16 + w * 8 + c;
  const bool hb  = (h != 0);

  // W2 tiles 4..7, 4 slabs, A-frag layout, K2-folded: 16KB
  __shared__ unsigned short w2lds[4][4][64][8];

  // build LDS frags: wave w builds fi = w*8 .. w*8+7 (tiles 4+fi>>2)
  for (int fi = w * 8; fi < w * 8 + 8; ++fi) {
    int tp = fi >> 2, kk = fi & 3;
    Frag f;
    #pragma unroll
    for (int j = 0; j < 8; ++j)
      f.u[j] = f2bf(W2[(kk * 32 + q * 8 + j) * HID + ((4 + tp) * 16 + m16)] * K2C);
    *(bf16x8*)&w2lds[tp][kk][lane][0] = f.v;
  }

  // ---- register preloads, K2-folded ----
  // W2 tiles 0..3 -> plain VGPR arrays (64 regs)
  Frag W2v[4][4];
  #pragma unroll
  for (int t = 0; t < 4; ++t)
    #pragma unroll
    for (int kk = 0; kk < 4; ++kk) {
      #pragma unroll
      for (int j = 0; j < 8; ++j)
        W2v[t][kk].u[j] = f2bf(W2[(kk * 32 + q * 8 + j) * HID + (t * 16 + m16)] * K2C);
    }
  // W1 for my 16 units: u = (2h+sl)*32 + q*8 + 2*pp (+1)
  f32x2 w1x[8], w1y[8];
  unsigned w1tp[8], bb1p[8];            // bf16-packed
  #pragma unroll
  for (int sl = 0; sl < 2; ++sl)
    #pragma unroll
    for (int pp = 0; pp < 4; ++pp) {
      int p = sl * 4 + pp;
      int u = (2 * h + sl) * 32 + q * 8 + 2 * pp;
      w1x[p] = f32x2{W1[0 * HID + u], W1[0 * HID + u + 1]} * bc(K2C);
      w1y[p] = f32x2{W1[1 * HID + u], W1[1 * HID + u + 1]} * bc(K2C);
      w1tp[p] = pack2bf(W1[4 * HID + u] * K2C, W1[4 * HID + u + 1] * K2C);
      bb1p[p] = pack2bf(b1[u] * K2C, b1[u + 1] * K2C);
    }
  // epilogue tables for MY tiles t' = h*4+p: units u2 = t'*16 + q*4 + rr
  unsigned b2pp[4][2];                  // bf16-packed b2*K2C pairs (b2==0)
  f32x2 w3n2[4][4];
  f32x2 w3s = bc(0.f);
  #pragma unroll
  for (int p = 0; p < 4; ++p) {
    int ub = (h * 4 + p) * 16 + q * 4;
    #pragma unroll
    for (int p2 = 0; p2 < 2; ++p2)
      b2pp[p][p2] = pack2bf(b2[ub + 2 * p2] * K2C, b2[ub + 2 * p2 + 1] * K2C);
    #pragma unroll
    for (int rr = 0; rr < 4; ++rr) {
      f32x2 w3 = f32x2{W3[(ub + rr) * 2 + 0], W3[(ub + rr) * 2 + 1]};
      w3s += w3;
      w3n2[p][rr] = w3 * bc(-2.f);
    }
  }
  const f32x2 b3v = f32x2{b3[0], b3[1]};

  __syncthreads();                      // w2lds ready (only barrier)

  f32x2 S = f32x2{r0[2 * s + 0], r0[2 * s + 1]};
  if (lane < 8) *(float2*)&out[(s * TT + 0) * 2] = make_float2(S.x, S.y);

  auto feval = [&](float tt, f32x2 st) -> f32x2 {
    const f32x2 sx = bc(st.x), sy = bc(st.y), tv = bc(tt);
    // ---- L1: my 2 slabs (8 tanh-pairs, 32 trans) ----
    unsigned own[2][4];
    #pragma unroll
    for (int sl = 0; sl < 2; ++sl)
      #pragma unroll
      for (int pp = 0; pp < 4; ++pp) {
        int p = sl * 4 + pp;
        f32x2 bb = f32x2{bflo(bb1p[p]), bfhi(bb1p[p])};
        f32x2 wt = f32x2{bflo(w1tp[p]), bfhi(w1tp[p])};
        f32x2 a = pk_fma(sx, w1x[p], bb);
        a = pk_fma(sy, w1y[p], a);
        a = pk_fma(tv, wt, a);
        f32x2 hv = tanh_pre(a);
        own[sl][pp] = pack2bf(hv.x, hv.y);
      }
    // ---- exchange with lane^8 (partner has the other 2 slabs) ----
    unsigned rcv[2][4];
    #pragma unroll
    for (int sl = 0; sl < 2; ++sl)
      #pragma unroll
      for (int d = 0; d < 4; ++d)
        rcv[sl][d] = __shfl_xor(own[sl][d], 8);
    // canonical slab-order B frags (cols 8..15 duplicate cols 0..7)
    Frag B[4];
    #pragma unroll
    for (int d = 0; d < 4; ++d) {
      B[0].d[d] = hb ? rcv[0][d] : own[0][d];
      B[1].d[d] = hb ? rcv[1][d] : own[1][d];
      B[2].d[d] = hb ? own[0][d] : rcv[0][d];
      B[3].d[d] = hb ? own[1][d] : rcv[1][d];
    }
    // ---- pair-fused MFMA+epilogue: pair p = tiles (p, p+4) ----
    f32x2 vsa[2] = {w3s, bc(0.f)};
    #pragma unroll
    for (int p = 0; p < 4; ++p) {
      f32x4 aA, aB;
      #pragma unroll
      for (int kk = 0; kk < 4; ++kk) {
        Frag lf;
        lf.v = *(const bf16x8*)&w2lds[p][kk][lane][0];
        aA = __builtin_amdgcn_mfma_f32_16x16x32_bf16(
            W2v[p][kk].v, B[kk].v,
            kk == 0 ? f32x4{0.f, 0.f, 0.f, 0.f} : aA, 0, 0, 0);
        aB = __builtin_amdgcn_mfma_f32_16x16x32_bf16(
            lf.v, B[kk].v,
            kk == 0 ? f32x4{0.f, 0.f, 0.f, 0.f} : aB, 0, 0, 0);
      }
      #pragma unroll
      for (int p2 = 0; p2 < 2; ++p2) {
        float e0 = hb ? aB[2 * p2]     : aA[2 * p2];
        float e1 = hb ? aB[2 * p2 + 1] : aA[2 * p2 + 1];
        f32x2 av = f32x2{e0 + bflo(b2pp[p][p2]), e1 + bfhi(b2pp[p][p2])};
        f32x2 qv = sig_q(av);
        vsa[p & 1] = pk_fma(bc(qv.x), w3n2[p][2 * p2 + 0], vsa[p & 1]);
        vsa[p & 1] = pk_fma(bc(qv.y), w3n2[p][2 * p2 + 1], vsa[p & 1]);
      }
    }
    f32x2 vs = vsa[0] + vsa[1];
    // reduce over the 8 lanes of sample c: xor8 (h), xor16/32 (q)
    float px = vs.x, py = vs.y;
    px += __shfl_xor(px, 8);  py += __shfl_xor(py, 8);
    px += __shfl_xor(px, 16); py += __shfl_xor(py, 16);
    px += __shfl_xor(px, 32); py += __shfl_xor(py, 32);
    return f32x2{px, py} + b3v;
  };

  #pragma unroll 1
  for (int iv = 0; iv < TT - 1; ++iv) {
    float t0 = tarr[iv], t1 = tarr[iv + 1];
    float dt = (t1 - t0) * 0.5f;
    #pragma unroll 1
    for (int ss = 0; ss < 2; ++ss) {
      float tb = (ss == 0) ? t0 : (t0 + dt);
      const f32x2 dtv = bc(dt);
      f32x2 k1 = feval(tb, S);
      f32x2 k2 = feval(tb + dt * F(1,5), pk_fma(bc(dt * F(1,5)), k1, S));
      f32x2 a3 = pk_fma(bc(F(9,40)), k2, bc(F(3,40)) * k1);
      f32x2 k3 = feval(tb + dt * F(3,10), pk_fma(dtv, a3, S));
      f32x2 a4 = pk_fma(bc(F(44,45)), k1,
                 pk_fma(bc(-F(56,15)), k2, bc(F(32,9)) * k3));
      f32x2 k4 = feval(tb + dt * F(4,5), pk_fma(dtv, a4, S));
      f32x2 a5 = pk_fma(bc(F(19372,6561)), k1,
                 pk_fma(bc(-F(25360,2187)), k2,
                 pk_fma(bc(F(64448,6561)), k3, bc(-F(212,729)) * k4)));
      f32x2 k5 = feval(tb + dt * F(8,9), pk_fma(dtv, a5, S));
      f32x2 a6 = pk_fma(bc(F(9017,3168)), k1,
                 pk_fma(bc(-F(355,33)), k2,
                 pk_fma(bc(F(46732,5247)), k3,
                 pk_fma(bc(F(49,176)), k4, bc(-F(5103,18656)) * k5))));
      f32x2 k6 = feval(tb + dt, pk_fma(dtv, a6, S));
      f32x2 fin = pk_fma(bc(F(35,384)), k1,
                  pk_fma(bc(F(500,1113)), k3,
                  pk_fma(bc(F(125,192)), k4,
                  pk_fma(bc(-F(2187,6784)), k5, bc(F(11,84)) * k6))));
      S = pk_fma(dtv, fin, S);
    }
    if (lane < 8)
      *(float2*)&out[(s * TT + iv + 1) * 2] = make_float2(S.x, S.y);
  }
}

extern "C" void kernel_launch(void* const* d_in, const int* in_sizes, int n_in,
                              void* d_out, int out_size, void* d_ws, size_t ws_size,
                              hipStream_t stream) {
  const float* r0 = (const float*)d_in[0];
  const float* t  = (const float*)d_in[1];
  const float* W1 = (const float*)d_in[2];
  const float* b1 = (const float*)d_in[3];
  const float* W2 = (const float*)d_in[4];
  const float* b2 = (const float*)d_in[5];
  const float* W3 = (const float*)d_in[6];
  const float* b3 = (const float*)d_in[7];
  float* out = (float*)d_out;
  const int B = in_sizes[0] / 2;        // 16384
  dim3 grid(B / 16), block(128);        // 1024 blocks x 2 waves (8 samp/wave)
  node_kernel<<<grid, block, 0, stream>>>(r0, t, W1, b1, W2, b2, W3, b3, out);
}

// Round 6
// 239.179 us; speedup vs baseline: 2.4328x; 2.4328x over previous
//
#include <hip/hip_runtime.h>

// AugmentedNeuralODE, round 19: kill the remat traffic (FETCH:WRITE 12:1 =
// compiler re-loads read-only tables every feval under its 128-reg budget).
// Lever: R13/R16-style asm AGPR parking pins a 256-reg (128 arch + 128 acc)
// allocation; R16 failed because the ARCH half still needed ~160. Fix:
//   * W2 all 8 tiles x 4 slabs -> AGPR (exactly 128), MFMA A-src direct.
//   * w1x/w1y/w1t/bb1 + w3n2/b2/w3s -> ~3.6KB LDS, broadcast reads per
//     feval (~44 ds ops, trivial BW); frees ~90 arch regs.
//   * anti-LICM: opaque asm on the LDS table pointer inside feval, else
//     LLVM hoists the loop-invariant ds_reads back into registers.
// Arch peak ~110-125 <= 128. Same math/order as R16-18 (absmax 0.03125):
// duplicate-column 2-wave blocks, shfl_xor(8) exchange, pair-fused
// epilogue, zero in-loop barriers. 1024 x 128, 2 waves/SIMD.

#define HID 128
#define TT  8
#define F(a,b) ((float)((double)(a)/(double)(b)))
#define K2C 2.8853900817779268f        // 2*log2(e), folded into W1/b1/W2/b2

typedef __attribute__((ext_vector_type(8))) short bf16x8;
typedef __attribute__((ext_vector_type(4))) float f32x4;
typedef __attribute__((ext_vector_type(2))) float f32x2;

union Frag { bf16x8 v; unsigned short u[8]; unsigned int d[4]; };

__device__ __forceinline__ f32x2 bc(float s) { return f32x2{s, s}; }
__device__ __forceinline__ f32x2 pk_fma(f32x2 a, f32x2 b, f32x2 c) {
#if __has_builtin(__builtin_elementwise_fma)
  return __builtin_elementwise_fma(a, b, c);
#else
  return a * b + c;
#endif
}
__device__ __forceinline__ float exp2_fast(float x) {
#if __has_builtin(__builtin_amdgcn_exp2f)
  return __builtin_amdgcn_exp2f(x);
#else
  return __builtin_exp2f(x);
#endif
}
__device__ __forceinline__ unsigned short f2bf(float f) {
  unsigned u = __builtin_bit_cast(unsigned, f);
  u += 0x7FFFu + ((u >> 16) & 1u);          // RNE
  return (unsigned short)(u >> 16);
}
__device__ __forceinline__ unsigned pack2bf(float a, float b) {
#if __has_builtin(__builtin_amdgcn_cvt_pk_bf16_f32)
  auto pk = __builtin_amdgcn_cvt_pk_bf16_f32(a, b);   // v_cvt_pk_bf16_f32
  return __builtin_bit_cast(unsigned, pk);
#else
  unsigned ua = __builtin_bit_cast(unsigned, a);
  unsigned ub = __builtin_bit_cast(unsigned, b);
  ua += 0x7FFFu + ((ua >> 16) & 1u);
  ub += 0x7FFFu + ((ub >> 16) & 1u);
  return __builtin_amdgcn_perm(ub, ua, 0x07060302u);
#endif
}
// u pre-scaled by 2*log2(e): q = 1/(exp2(u)+1), separate rcp per element.
__device__ __forceinline__ f32x2 sig_q(f32x2 u) {
  f32x2 e;
  e.x = exp2_fast(u.x);
  e.y = exp2_fast(u.y);
  f32x2 d = e + bc(1.0f);
  f32x2 q;
  q.x = __builtin_amdgcn_rcpf(d.x);
  q.y = __builtin_amdgcn_rcpf(d.y);
  return q;
}
__device__ __forceinline__ f32x2 tanh_pre(f32x2 u) {   // tanh = 1 - 2q
  return pk_fma(bc(-2.0f), sig_q(u), bc(1.0f));
}

// per-lane-class (cls = h*4+q) broadcast tables
struct Tables {
  f32x2 w1x[8][8], w1y[8][8], w1t[8][8], bb1[8][8];   // [cls][p], K2C-folded
  f32x4 w3n2[8][4][2];     // [cls][p][p2] = {-2w3 for rr=2p2, rr=2p2+1}
  f32x4 b2k[8][4];         // [cls][p] = b2[ub..ub+3]*K2C
  f32x2 w3s[8];            // [cls] = sum of w3 over class rows
};

__global__ __launch_bounds__(128, 2) void node_kernel(
    const float* __restrict__ r0, const float* __restrict__ tarr,
    const float* __restrict__ W1, const float* __restrict__ b1,
    const float* __restrict__ W2, const float* __restrict__ b2,
    const float* __restrict__ W3, const float* __restrict__ b3,
    float* __restrict__ out)
{
  const int tid  = (int)threadIdx.x;
  const int w    = tid >> 6;            // wave 0/1
  const int lane = tid & 63;
  const int q    = lane >> 4;           // 0..3
  const int h    = (lane >> 3) & 1;     // half within 16-col group
  const int c    = lane & 7;            // my sample (0..7 within wave)
  const int m16  = lane & 15;           // MFMA row/col index
  const int cls  = h * 4 + q;           // lane class for tables
  const int s    = (int)blockIdx.x * 16 + w * 8 + c;
  const bool hb  = (h != 0);

  __shared__ Tables tb;                 // ~3.6 KB

  // ---- build LDS tables: one writer lane per class (wave 0, c==0) ----
  if (w == 0 && c == 0) {
    #pragma unroll
    for (int p = 0; p < 8; ++p) {
      int sl = p >> 2, pp = p & 3;
      int u = (2 * h + sl) * 32 + q * 8 + 2 * pp;
      tb.w1x[cls][p] = f32x2{W1[0 * HID + u], W1[0 * HID + u + 1]} * bc(K2C);
      tb.w1y[cls][p] = f32x2{W1[1 * HID + u], W1[1 * HID + u + 1]} * bc(K2C);
      tb.w1t[cls][p] = f32x2{W1[4 * HID + u], W1[4 * HID + u + 1]} * bc(K2C);
      tb.bb1[cls][p] = f32x2{b1[u], b1[u + 1]} * bc(K2C);
    }
    f32x2 ws = bc(0.f);
    #pragma unroll
    for (int p = 0; p < 4; ++p) {
      int ub = (h * 4 + p) * 16 + q * 4;
      tb.b2k[cls][p] = f32x4{b2[ub] * K2C, b2[ub + 1] * K2C,
                             b2[ub + 2] * K2C, b2[ub + 3] * K2C};
      #pragma unroll
      for (int p2 = 0; p2 < 2; ++p2) {
        f32x2 w3a = f32x2{W3[(ub + 2 * p2) * 2], W3[(ub + 2 * p2) * 2 + 1]};
        f32x2 w3b = f32x2{W3[(ub + 2 * p2 + 1) * 2], W3[(ub + 2 * p2 + 1) * 2 + 1]};
        ws += w3a + w3b;
        tb.w3n2[cls][p][p2] =
            f32x4{-2.f * w3a.x, -2.f * w3a.y, -2.f * w3b.x, -2.f * w3b.y};
      }
    }
    tb.w3s[cls] = ws;
  }

  // ---- W2: all 8 tiles x 4 slabs -> AGPR (128 regs), K2C-folded ----
  Frag W2a[8][4];
  #pragma unroll
  for (int t = 0; t < 8; ++t)
    #pragma unroll
    for (int kk = 0; kk < 4; ++kk) {
      #pragma unroll
      for (int j = 0; j < 8; ++j)
        W2a[t][kk].u[j] = f2bf(W2[(kk * 32 + q * 8 + j) * HID + (t * 16 + m16)] * K2C);
      asm volatile("" : "+a"(W2a[t][kk].v));   // park in AGPR (MFMA A-src)
    }

  const f32x2 b3v = f32x2{b3[0], b3[1]};

  __syncthreads();                      // tables ready (only barrier)

  f32x2 S = f32x2{r0[2 * s + 0], r0[2 * s + 1]};
  if (lane < 8) *(float2*)&out[(s * TT + 0) * 2] = make_float2(S.x, S.y);

  auto feval = [&](float tt, f32x2 st) -> f32x2 {
    // opaque table pointer: forbid cross-feval hoisting/CSE of ds_reads
    const Tables* T = &tb;
    asm volatile("" : "+v"(T));
    const f32x2 sx = bc(st.x), sy = bc(st.y), tv = bc(tt);
    // ---- L1: my 2 slabs (8 tanh-pairs, 32 trans), tables from LDS ----
    unsigned own[2][4];
    #pragma unroll
    for (int sl = 0; sl < 2; ++sl)
      #pragma unroll
      for (int pp = 0; pp < 4; ++pp) {
        int p = sl * 4 + pp;
        f32x2 a = pk_fma(sx, T->w1x[cls][p], T->bb1[cls][p]);
        a = pk_fma(sy, T->w1y[cls][p], a);
        a = pk_fma(tv, T->w1t[cls][p], a);
        f32x2 hv = tanh_pre(a);
        own[sl][pp] = pack2bf(hv.x, hv.y);
      }
    // ---- exchange with lane^8 (partner has the other 2 slabs) ----
    unsigned rcv[2][4];
    #pragma unroll
    for (int sl = 0; sl < 2; ++sl)
      #pragma unroll
      for (int d = 0; d < 4; ++d)
        rcv[sl][d] = __shfl_xor(own[sl][d], 8);
    // canonical slab-order B frags (cols 8..15 duplicate cols 0..7)
    Frag B[4];
    #pragma unroll
    for (int d = 0; d < 4; ++d) {
      B[0].d[d] = hb ? rcv[0][d] : own[0][d];
      B[1].d[d] = hb ? rcv[1][d] : own[1][d];
      B[2].d[d] = hb ? own[0][d] : rcv[0][d];
      B[3].d[d] = hb ? own[1][d] : rcv[1][d];
    }
    // ---- pair-fused MFMA+epilogue: pair p = tiles (p, p+4) ----
    f32x2 vsa[2] = {f32x2(T->w3s[cls]), bc(0.f)};
    #pragma unroll
    for (int p = 0; p < 4; ++p) {
      f32x4 aA, aB;
      #pragma unroll
      for (int kk = 0; kk < 4; ++kk) {
        aA = __builtin_amdgcn_mfma_f32_16x16x32_bf16(
            W2a[p][kk].v, B[kk].v,
            kk == 0 ? f32x4{0.f, 0.f, 0.f, 0.f} : aA, 0, 0, 0);
        aB = __builtin_amdgcn_mfma_f32_16x16x32_bf16(
            W2a[p + 4][kk].v, B[kk].v,
            kk == 0 ? f32x4{0.f, 0.f, 0.f, 0.f} : aB, 0, 0, 0);
      }
      f32x4 b2q = T->b2k[cls][p];
      #pragma unroll
      for (int p2 = 0; p2 < 2; ++p2) {
        f32x4 w3q = T->w3n2[cls][p][p2];
        float e0 = hb ? aB[2 * p2]     : aA[2 * p2];
        float e1 = hb ? aB[2 * p2 + 1] : aA[2 * p2 + 1];
        f32x2 av = f32x2{e0 + b2q[2 * p2], e1 + b2q[2 * p2 + 1]};
        f32x2 qv = sig_q(av);
        vsa[p & 1] = pk_fma(bc(qv.x), f32x2{w3q[0], w3q[1]}, vsa[p & 1]);
        vsa[p & 1] = pk_fma(bc(qv.y), f32x2{w3q[2], w3q[3]}, vsa[p & 1]);
      }
    }
    f32x2 vs = vsa[0] + vsa[1];
    // reduce over the 8 lanes of sample c: xor8 (h), xor16/32 (q)
    float px = vs.x, py = vs.y;
    px += __shfl_xor(px, 8);  py += __shfl_xor(py, 8);
    px += __shfl_xor(px, 16); py += __shfl_xor(py, 16);
    px += __shfl_xor(px, 32); py += __shfl_xor(py, 32);
    return f32x2{px, py} + b3v;
  };

  #pragma unroll 1
  for (int iv = 0; iv < TT - 1; ++iv) {
    float t0 = tarr[iv], t1 = tarr[iv + 1];
    float dt = (t1 - t0) * 0.5f;
    #pragma unroll 1
    for (int ss = 0; ss < 2; ++ss) {
      float tb0 = (ss == 0) ? t0 : (t0 + dt);
      const f32x2 dtv = bc(dt);
      f32x2 k1 = feval(tb0, S);
      f32x2 k2 = feval(tb0 + dt * F(1,5), pk_fma(bc(dt * F(1,5)), k1, S));
      f32x2 a3 = pk_fma(bc(F(9,40)), k2, bc(F(3,40)) * k1);
      f32x2 k3 = feval(tb0 + dt * F(3,10), pk_fma(dtv, a3, S));
      f32x2 a4 = pk_fma(bc(F(44,45)), k1,
                 pk_fma(bc(-F(56,15)), k2, bc(F(32,9)) * k3));
      f32x2 k4 = feval(tb0 + dt * F(4,5), pk_fma(dtv, a4, S));
      f32x2 a5 = pk_fma(bc(F(19372,6561)), k1,
                 pk_fma(bc(-F(25360,2187)), k2,
                 pk_fma(bc(F(64448,6561)), k3, bc(-F(212,729)) * k4)));
      f32x2 k5 = feval(tb0 + dt * F(8,9), pk_fma(dtv, a5, S));
      f32x2 a6 = pk_fma(bc(F(9017,3168)), k1,
                 pk_fma(bc(-F(355,33)), k2,
                 pk_fma(bc(F(46732,5247)), k3,
                 pk_fma(bc(F(49,176)), k4, bc(-F(5103,18656)) * k5))));
      f32x2 k6 = feval(tb0 + dt, pk_fma(dtv, a6, S));
      f32x2 fin = pk_fma(bc(F(35,384)), k1,
                  pk_fma(bc(F(500,1113)), k3,
                  pk_fma(bc(F(125,192)), k4,
                  pk_fma(bc(-F(2187,6784)), k5, bc(F(11,84)) * k6))));
      S = pk_fma(dtv, fin, S);
    }
    if (lane < 8)
      *(float2*)&out[(s * TT + iv + 1) * 2] = make_float2(S.x, S.y);
  }
}

extern "C" void kernel_launch(void* const* d_in, const int* in_sizes, int n_in,
                              void* d_out, int out_size, void* d_ws, size_t ws_size,
                              hipStream_t stream) {
  const float* r0 = (const float*)d_in[0];
  const float* t  = (const float*)d_in[1];
  const float* W1 = (const float*)d_in[2];
  const float* b1 = (const float*)d_in[3];
  const float* W2 = (const float*)d_in[4];
  const float* b2 = (const float*)d_in[5];
  const float* W3 = (const float*)d_in[6];
  const float* b3 = (const float*)d_in[7];
  float* out = (float*)d_out;
  const int B = in_sizes[0] / 2;        // 16384
  dim3 grid(B / 16), block(128);        // 1024 blocks x 2 waves (8 samp/wave)
  node_kernel<<<grid, block, 0, stream>>>(r0, t, W1, b1, W2, b2, W3, b3, out);
}